// Round 8
// baseline (3021.227 us; speedup 1.0000x reference)
//
#include <hip/hip_runtime.h>

typedef unsigned short u16;
typedef unsigned int   u32;
typedef __attribute__((ext_vector_type(8))) short s8v;            // MFMA bf16 frag
typedef __attribute__((ext_vector_type(8))) unsigned short u8v;
typedef __attribute__((ext_vector_type(4))) unsigned short u4h;
typedef __attribute__((ext_vector_type(4))) float f32x4;

__device__ __forceinline__ float bf2f(u16 v) {
    union { u32 u; float f; } x; x.u = ((u32)v) << 16; return x.f;
}
__device__ __forceinline__ u16 f2bf(float f) {
    union { float f; u32 u; } x; x.f = f;
    return (u16)((x.u + 0x7fffu + ((x.u >> 16) & 1u)) >> 16);
}
__device__ __forceinline__ float sigf(float x)  { return 1.0f / (1.0f + __expf(-x)); }
__device__ __forceinline__ float tanhf_(float x){ return 1.0f - 2.0f / (__expf(2.0f * x) + 1.0f); }

constexpr int Bb = 256, Tt = 32, Ss = 2048, Aa = 64, Pp = 128, SAPd = 2240;

typedef const __attribute__((address_space(1))) unsigned int* gp1_t;
typedef __attribute__((address_space(3))) unsigned int* lp3_t;
__device__ __forceinline__ void gl16(const void* g, void* l) {
    __builtin_amdgcn_global_load_lds((gp1_t)g, (lp3_t)l, 16, 0, 0);
}
#define VMWAIT(n) asm volatile("s_waitcnt vmcnt(" #n ")" ::: "memory")

// XCD-aware decode: hardware round-robins linear block id across the 8 XCDs,
// so xcd = id&7.  Give each XCD a contiguous slice of the N dimension (bx).
// Bijective for power-of-two params; pure renumbering (correctness-neutral).
template<int NBXPX, int NBY>
__device__ __forceinline__ void xcd_decode(int& bx, int& by) {
    int id  = blockIdx.x;
    int xcd = id & 7, i = id >> 3;
    bx = xcd * NBXPX + (i & (NBXPX - 1));
    by = i / NBXPX;
}

// 1 = bf16 inputs; detector kept as insurance.
__global__ void detect_k(const u32* __restrict__ st, int* __restrict__ flag) {
    u32 w = st[threadIdx.x];
    int e = (w >> 7) & 0xFF;
    unsigned long long m = __ballot(e >= 100 && e <= 140);
    if (threadIdx.x == 0) flag[0] = (__popcll(m) >= 32) ? 1 : 0;
}

// hs0 build + rewards zero + (big ws) fc1s = fc1_W[:,:S] + fc1_W[:,S:]
__global__ __launch_bounds__(256)
void prep_k(const void* __restrict__ state, const void* __restrict__ act,
            const void* __restrict__ latent, const void* __restrict__ fc1W,
            u16* __restrict__ hs, u16* __restrict__ fc1s, float* __restrict__ rewbuf,
            const int* __restrict__ flagp, int big)
{
    const bool bfe = (flagp[0] == 1);
    int g0 = blockIdx.x * 256 + threadIdx.x;
    int stride = gridDim.x * 256;
    for (int i = g0; i < Bb * SAPd; i += stride) {
        int b = i / SAPd, k = i - b * SAPd;
        const void* p; size_t src;
        if (k < Ss)           { p = state;  src = (size_t)b * Ss + k; }
        else if (k < Ss + Aa) { p = act;    src = (size_t)b * (Tt * Aa) + (k - Ss); }
        else                  { p = latent; src = (size_t)b * Pp + (k - Ss - Aa); }
        hs[i] = bfe ? ((const u16*)p)[src] : f2bf(((const float*)p)[src]);
    }
    for (int i = g0; i < Tt * Bb; i += stride) rewbuf[i] = 0.0f;
    if (big) {
        for (int i = g0; i < Ss * Ss; i += stride) {
            int n = i >> 11, k = i & 2047;
            float s;
            if (bfe) s = bf2f(((const u16*)fc1W)[(size_t)n * 4096 + k])
                       + bf2f(((const u16*)fc1W)[(size_t)n * 4096 + 2048 + k]);
            else     s = ((const float*)fc1W)[(size_t)n * 4096 + k]
                       + ((const float*)fc1W)[(size_t)n * 4096 + 2048 + k];
            fc1s[i] = f2bf(s);
        }
    }
}

// C[256 x 2048] = relu(A @ W^T (+bias)).  Tile 32(M) x 64(N), 4 waves =
// 2 col-halves (ct) x 2 K-halves (khw).  Per wave-iter 4 ds_read -> 4 MFMA.
// 3 LDS bufs, depth-2 prefetch, counted vmcnt(3), XOR swizzle both-sides.
// Unchanged from R6 (verified at 2708us total).
template<int K, bool BIAS, bool WC, bool FOLD, bool ACT, bool WBF>
__global__ __launch_bounds__(256)
void gemm_k(const u16* __restrict__ Ap, const void* __restrict__ Wp,
            const void* __restrict__ biasp, u16* __restrict__ outp,
            float* __restrict__ cellp,
            u16* __restrict__ hsp, const void* __restrict__ actp, int t,
            const int* __restrict__ flagp)
{
    constexpr int NK = K / 64;
    __shared__ __align__(16) char smem[36864 + 8192];   // 3 x (4KB A + 8KB B) + red
    const bool bfe = (flagp[0] == 1);
    const int tid = threadIdx.x;
    const int lane = tid & 63, w = tid >> 6, m16 = lane & 15, q = lane >> 4;
    const int ct = w & 1, khw = w >> 1;
    int bx, by; xcd_decode<4, 8>(bx, by);
    const int r0 = by * 32, c0 = bx * 64;

    if (ACT) {          // refresh act_t slice of hs before the fc GEMM reads it
        if (by == 0) {
            int i = bx * 512 + tid * 2;                 // 32 bx-values x 512 = 16384
            int b = i >> 6, a2 = i & 63;
            if (bfe) {
                u32 v = *(const u32*)((const u16*)actp + ((size_t)b * Tt + t) * Aa + a2);
                *(u32*)(hsp + (size_t)b * SAPd + Ss + a2) = v;
            } else {
                const float* s = (const float*)actp + ((size_t)b * Tt + t) * Aa + a2;
                *(u32*)(hsp + (size_t)b * SAPd + Ss + a2) =
                    (u32)f2bf(s[0]) | ((u32)f2bf(s[1]) << 16);
            }
            VMWAIT(0);                                  // retire before counted pipeline
        }
    }

    const int srow = tid >> 3, sch = tid & 7;           // A-tile: 32 rows x 8 chunks
    const int fr2 = 32 + srow;                          // B-tile rows 32..63
    f32x4 acc[4] = {};                                  // [cf*2+af]
    const bool mainp = (WBF || bfe) && !FOLD;

    auto COMPUTE = [&](int p) {
        const char* bufA = smem + p * 12288;
        const char* bufB = bufA + 4096;
        const int sw = (m16 & 7) << 4;
        const int cb = ((khw << 6) | (q << 4)) ^ sw;
        s8v a0 = *(const s8v*)(bufA + m16 * 128 + cb);
        s8v a1 = *(const s8v*)(bufA + (16 + m16) * 128 + cb);
        s8v b0 = *(const s8v*)(bufB + (ct * 32 + m16) * 128 + cb);
        s8v b1 = *(const s8v*)(bufB + (ct * 32 + 16 + m16) * 128 + cb);
        acc[0] = __builtin_amdgcn_mfma_f32_16x16x32_bf16(a0, b0, acc[0], 0, 0, 0);
        acc[1] = __builtin_amdgcn_mfma_f32_16x16x32_bf16(a1, b0, acc[1], 0, 0, 0);
        acc[2] = __builtin_amdgcn_mfma_f32_16x16x32_bf16(a0, b1, acc[2], 0, 0, 0);
        acc[3] = __builtin_amdgcn_mfma_f32_16x16x32_bf16(a1, b1, acc[3], 0, 0, 0);
    };

    if (mainp) {
        const u16* W16 = (const u16*)Wp;
        auto STAGE = [&](int kt, int p) {
            char* bufA = smem + p * 12288;
            char* bufB = bufA + 4096;
            int kb = kt * 64;
            gl16(Ap + (size_t)(r0 + srow) * K + kb + ((sch ^ (srow & 7)) * 8),
                 bufA + w * 1024);
            gl16(W16 + (size_t)(c0 + srow) * K + kb + ((sch ^ (srow & 7)) * 8),
                 bufB + w * 1024);
            gl16(W16 + (size_t)(c0 + fr2) * K + kb + ((sch ^ (fr2 & 7)) * 8),
                 bufB + 4096 + w * 1024);
        };
        STAGE(0, 0); STAGE(1, 1);
        for (int k = 0; k < NK - 2; k++) {
            VMWAIT(3);                                  // tile k landed (k+1 in flight)
            __builtin_amdgcn_s_barrier();               // k visible to all; k-1 free
            STAGE(k + 2, (k + 2) % 3);
            COMPUTE(k % 3);
        }
        VMWAIT(3);
        __builtin_amdgcn_s_barrier();
        COMPUTE((NK - 2) % 3);
        VMWAIT(0);
        __builtin_amdgcn_s_barrier();
        COMPUTE((NK - 1) % 3);
    } else {
        // fallback: reg-staged double-buffer (FOLD and/or f32 weights)
        u8v fa; u8v rbh[4]; float4 rff[8];
        auto ISSUE = [&](int kt) {
            int kb = kt * 64;
            fa = *(const u8v*)(Ap + (size_t)(r0 + srow) * K + kb + sch * 8);
            if (FOLD) {
                if (bfe) {
                    const u16* p1 = (const u16*)Wp + (size_t)(c0 + srow) * (2 * K) + kb + sch * 8;
                    rbh[0] = *(const u8v*)p1; rbh[1] = *(const u8v*)(p1 + K);
                    const u16* p2 = (const u16*)Wp + (size_t)(c0 + fr2) * (2 * K) + kb + sch * 8;
                    rbh[2] = *(const u8v*)p2; rbh[3] = *(const u8v*)(p2 + K);
                } else {
                    const float* p1 = (const float*)Wp + (size_t)(c0 + srow) * (2 * K) + kb + sch * 8;
                    rff[0] = *(const float4*)p1;       rff[1] = *(const float4*)(p1 + 4);
                    rff[2] = *(const float4*)(p1 + K); rff[3] = *(const float4*)(p1 + K + 4);
                    const float* p2 = (const float*)Wp + (size_t)(c0 + fr2) * (2 * K) + kb + sch * 8;
                    rff[4] = *(const float4*)p2;       rff[5] = *(const float4*)(p2 + 4);
                    rff[6] = *(const float4*)(p2 + K); rff[7] = *(const float4*)(p2 + K + 4);
                }
            } else {
                const float* p1 = (const float*)Wp + (size_t)(c0 + srow) * K + kb + sch * 8;
                rff[0] = *(const float4*)p1; rff[1] = *(const float4*)(p1 + 4);
                const float* p2 = (const float*)Wp + (size_t)(c0 + fr2) * K + kb + sch * 8;
                rff[2] = *(const float4*)p2; rff[3] = *(const float4*)(p2 + 4);
            }
        };
        auto COMMIT = [&](int p) {
            char* bufA = smem + p * 12288;
            char* bufB = bufA + 4096;
            *(u8v*)(bufA + srow * 128 + ((sch ^ (srow & 7)) * 16)) = fa;
            u8v v1, v2;
            if (FOLD) {
                if (bfe) {
                    #pragma unroll
                    for (int j = 0; j < 8; j++) {
                        v1[j] = f2bf(bf2f(rbh[0][j]) + bf2f(rbh[1][j]));
                        v2[j] = f2bf(bf2f(rbh[2][j]) + bf2f(rbh[3][j]));
                    }
                } else {
                    float a0[8], a1[8], b0[8], b1[8];
                    *(float4*)&a0[0] = rff[0]; *(float4*)&a0[4] = rff[1];
                    *(float4*)&a1[0] = rff[2]; *(float4*)&a1[4] = rff[3];
                    *(float4*)&b0[0] = rff[4]; *(float4*)&b0[4] = rff[5];
                    *(float4*)&b1[0] = rff[6]; *(float4*)&b1[4] = rff[7];
                    #pragma unroll
                    for (int j = 0; j < 8; j++) {
                        v1[j] = f2bf(a0[j] + a1[j]);
                        v2[j] = f2bf(b0[j] + b1[j]);
                    }
                }
            } else {
                float a0[8], a1[8];
                *(float4*)&a0[0] = rff[0]; *(float4*)&a0[4] = rff[1];
                *(float4*)&a1[0] = rff[2]; *(float4*)&a1[4] = rff[3];
                #pragma unroll
                for (int j = 0; j < 8; j++) { v1[j] = f2bf(a0[j]); v2[j] = f2bf(a1[j]); }
            }
            *(u8v*)(bufB + srow * 128 + ((sch ^ (srow & 7)) * 16)) = v1;
            *(u8v*)(bufB + fr2 * 128 + ((sch ^ (fr2 & 7)) * 16)) = v2;
        };
        ISSUE(0);
        for (int k = 0; k < NK; k++) {
            __syncthreads();
            COMMIT(k & 1);
            __syncthreads();
            if (k + 1 < NK) ISSUE(k + 1);
            COMPUTE(k & 1);
        }
    }

    // K-half reduction (red lives past the 3 buffers -> no overlay hazard)
    f32x4* red = (f32x4*)(smem + 36864);
    if (khw == 1) {
        #pragma unroll
        for (int f = 0; f < 4; f++) red[(ct * 4 + f) * 64 + lane] = acc[f];
    }
    __syncthreads();
    if (khw == 0) {
        #pragma unroll
        for (int f = 0; f < 4; f++) acc[f] += red[(ct * 4 + f) * 64 + lane];
        #pragma unroll
        for (int cf = 0; cf < 2; cf++) {
            const int col = c0 + ct * 32 + cf * 16 + m16;
            float bv = 0.0f;
            if (BIAS) bv = bfe ? bf2f(((const u16*)biasp)[col]) : ((const float*)biasp)[col];
            #pragma unroll
            for (int af = 0; af < 2; af++) {
                f32x4 a = acc[cf * 2 + af];
                #pragma unroll
                for (int r = 0; r < 4; r++) {
                    int row = r0 + af * 16 + q * 4 + r;
                    float v = fmaxf(a[r] + bv, 0.0f);
                    outp[(size_t)row * 2048 + col] = f2bf(v);
                    if (WC) cellp[(size_t)row * 2048 + col] = v;
                }
            }
        }
    }
}

// Fused: cc = relu(x2 @ W_W^T) + LSTM gates + cell + h' (hs & preds) + reward partial.
// Tile 128(M rows) x 16 j (x 4 gates = 64 B rows).  256 thr = 4 waves; wave w
// owns rows w*32..+31 over the FULL K-step -> acc is final, NO cross-wave
// reduction.  Grid 256 (1 block/CU): staged 192MB vs R6's 268MB.
// Per K-step: A 16 segs + B 8 segs = 6 gl16/thread, counted vmcnt(6).
// sched_barrier(0) after each s_barrier: s_barrier is not a compiler memory
// fence; pin LDS ops from crossing it (suspected R7 race).
// B-tile row b <-> W_W row (b>>4)*2048 + j0 + (b&15).
__global__ __launch_bounds__(256)
void wgates_k(const u16* __restrict__ Ap, const void* __restrict__ Wp,
              float* __restrict__ cbuf, u16* __restrict__ hsp,
              void* __restrict__ dout, const void* __restrict__ rwWp,
              float* __restrict__ rewbuf, int t, const int* __restrict__ flagp)
{
    constexpr int K = 2048, NK = 32;
    __shared__ __align__(16) char smem[73728];          // 3 x (16KB A + 8KB B)
    const bool bfe = (flagp[0] == 1);
    const int tid = threadIdx.x;
    const int lane = tid & 63, w = tid >> 6, m16 = lane & 15, q = lane >> 4;
    int bx, by; xcd_decode<16, 2>(bx, by);
    const int r0 = by * 128, j0 = bx * 16;

    const int srow8 = lane >> 3, sch = lane & 7;        // within-segment row/chunk
    f32x4 acc[8] = {};                                  // [cf*2+af]

    auto COMPUTE = [&](int p) {
        const char* bufA = smem + p * 24576;
        const char* bufB = bufA + 16384;
        const int sw = (m16 & 7) << 4;
        #pragma unroll
        for (int kh = 0; kh < 2; kh++) {
            const int cb = ((kh << 6) | (q << 4)) ^ sw;
            s8v a0 = *(const s8v*)(bufA + (w * 32 + m16) * 128 + cb);
            s8v a1 = *(const s8v*)(bufA + (w * 32 + 16 + m16) * 128 + cb);
            #pragma unroll
            for (int cf = 0; cf < 4; cf++) {
                s8v b = *(const s8v*)(bufB + (cf * 16 + m16) * 128 + cb);
                acc[cf * 2 + 0] = __builtin_amdgcn_mfma_f32_16x16x32_bf16(a0, b, acc[cf * 2 + 0], 0, 0, 0);
                acc[cf * 2 + 1] = __builtin_amdgcn_mfma_f32_16x16x32_bf16(a1, b, acc[cf * 2 + 1], 0, 0, 0);
            }
        }
    };

    if (bfe) {
        const u16* W16 = (const u16*)Wp;
        auto STAGE = [&](int kt, int p) {
            char* bufA = smem + p * 24576;
            char* bufB = bufA + 16384;
            int kb = kt * 64;
            #pragma unroll
            for (int i = 0; i < 4; i++) {               // A: 16 segs, 4 per wave
                int s = w * 4 + i;
                int row = s * 8 + srow8;                // 0..127
                int cg = sch ^ (row & 7);
                gl16(Ap + (size_t)(r0 + row) * K + kb + cg * 8, bufA + s * 1024);
            }
            #pragma unroll
            for (int i = 0; i < 2; i++) {               // B: 8 segs, 2 per wave
                int s = w * 2 + i;
                int row = s * 8 + srow8;                // 0..63
                int wr = (row >> 4) * 2048 + j0 + (row & 15);
                int cg = sch ^ (row & 7);
                gl16(W16 + (size_t)wr * K + kb + cg * 8, bufB + s * 1024);
            }
        };
        STAGE(0, 0); STAGE(1, 1);
        for (int k = 0; k < NK - 2; k++) {
            VMWAIT(6);                                  // 6 gl16/thread/STAGE
            __builtin_amdgcn_s_barrier();
            __builtin_amdgcn_sched_barrier(0);
            STAGE(k + 2, (k + 2) % 3);
            COMPUTE(k % 3);
        }
        VMWAIT(6);
        __builtin_amdgcn_s_barrier();
        __builtin_amdgcn_sched_barrier(0);
        COMPUTE((NK - 2) % 3);
        VMWAIT(0);
        __builtin_amdgcn_s_barrier();
        __builtin_amdgcn_sched_barrier(0);
        COMPUTE((NK - 1) % 3);
    } else {
        // fallback: A via gl16, B (f32 W_W) reg-staged (swizzled ds_write)
        float4 rff[4];
        const int brow = tid >> 2;                      // 64 rows x (2x2 chunks)
        const int wrf = (brow >> 4) * 2048 + j0 + (brow & 15);
        auto ISSUE = [&](int kt) {
            int kb = kt * 64;
            #pragma unroll
            for (int i = 0; i < 2; i++) {
                int c = (tid & 3) * 2 + i, cg = c ^ (brow & 7);
                const float* p1 = (const float*)Wp + (size_t)wrf * K + kb + cg * 8;
                rff[2 * i]     = *(const float4*)p1;
                rff[2 * i + 1] = *(const float4*)(p1 + 4);
            }
        };
        auto STAGE_A = [&](int kt, int p) {
            char* bufA = smem + p * 24576;
            int kb = kt * 64;
            #pragma unroll
            for (int i = 0; i < 4; i++) {
                int s = w * 4 + i;
                int row = s * 8 + srow8;
                int cg = sch ^ (row & 7);
                gl16(Ap + (size_t)(r0 + row) * K + kb + cg * 8, bufA + s * 1024);
            }
        };
        auto COMMIT = [&](int p) {
            char* bufB = smem + p * 24576 + 16384;
            #pragma unroll
            for (int i = 0; i < 2; i++) {
                int c = (tid & 3) * 2 + i;
                float a0[8];
                *(float4*)&a0[0] = rff[2 * i]; *(float4*)&a0[4] = rff[2 * i + 1];
                u8v v;
                #pragma unroll
                for (int j = 0; j < 8; j++) v[j] = f2bf(a0[j]);
                *(u8v*)(bufB + brow * 128 + c * 16) = v;
            }
        };
        ISSUE(0); STAGE_A(0, 0);
        for (int k = 0; k < NK; k++) {
            __syncthreads();                 // drains vmcnt: A(k) in LDS, B(k) in regs
            COMMIT(k & 1);
            __syncthreads();
            if (k + 1 < NK) { STAGE_A(k + 1, (k + 1) & 1); ISSUE(k + 1); }
            COMPUTE(k & 1);
        }
    }

    // epilogue: gbuf overlays buf0+start of buf1 -> fence all tile reads first
    __syncthreads();
    float* gbuf = (float*)smem;              // [128 rows][16 j][4 gates] fp32 = 32KB
    #pragma unroll
    for (int af = 0; af < 2; af++)
        #pragma unroll
        for (int r = 0; r < 4; r++) {
            int row = w * 32 + af * 16 + q * 4 + r;
            f32x4 gv;
            #pragma unroll
            for (int cf = 0; cf < 4; cf++) gv[cf] = fmaxf(acc[cf * 2 + af][r], 0.0f);
            ((f32x4*)gbuf)[row * 16 + m16] = gv;        // [row][j=m16][gate 0..3]
        }
    __syncthreads();

    const int row = tid >> 1, j8 = (tid & 1) * 8;       // 256 thr = 128 rows x 2
    const int grow = r0 + row, jcol = j0 + j8;
    float4 cold0 = *(const float4*)&cbuf[(size_t)grow * 2048 + jcol];
    float4 cold1 = *(const float4*)&cbuf[(size_t)grow * 2048 + jcol + 4];
    float coldv[8] = { cold0.x, cold0.y, cold0.z, cold0.w,
                       cold1.x, cold1.y, cold1.z, cold1.w };
    float rw8[8];
    #pragma unroll
    for (int u = 0; u < 8; u++)
        rw8[u] = bfe ? bf2f(((const u16*)rwWp)[jcol + u]) : ((const float*)rwWp)[jcol + u];

    float cn[8], hnf[8]; u8v hv;
    float rsum = 0.0f;
    #pragma unroll
    for (int u = 0; u < 8; u++) {
        const float* gq = &gbuf[((row * 16) + j8 + u) * 4];
        float ig = sigf(gq[0]), fg = sigf(gq[1]), og = sigf(gq[2]), tg = tanhf_(gq[3]);
        float c_ = fg * coldv[u] + ig * tg;
        float hn = og * tanhf_(c_);
        cn[u] = c_; hnf[u] = hn; hv[u] = f2bf(hn);
        rsum += hn * rw8[u];
    }
    *(float4*)&cbuf[(size_t)grow * 2048 + jcol]     = *(float4*)&cn[0];
    *(float4*)&cbuf[(size_t)grow * 2048 + jcol + 4] = *(float4*)&cn[4];
    *(u8v*)&hsp[(size_t)grow * SAPd + jcol] = hv;
    size_t pb = ((size_t)t * 256 + grow) * 2048 + jcol;
    if (bfe) *(u8v*)&((u16*)dout)[pb] = hv;
    else {
        #pragma unroll
        for (int u = 0; u < 8; u++) ((float*)dout)[pb + u] = hnf[u];
    }

    rsum += __shfl_xor(rsum, 1);
    if ((tid & 1) == 0) atomicAdd(&rewbuf[t * 256 + grow], rsum);
}

__global__ void rewfin_k(const float* __restrict__ rewbuf, void* __restrict__ dout,
                         const void* __restrict__ rwb, const int* __restrict__ flagp) {
    const bool bfe = (flagp[0] == 1);
    int i = blockIdx.x * 256 + threadIdx.x;        // grid 32 -> 8192
    float rb = bfe ? bf2f(((const u16*)rwb)[0]) : ((const float*)rwb)[0];
    float v = rewbuf[i] + rb;
    size_t o = (size_t)Tt * Bb * Ss + i;           // 16777216
    if (bfe) ((u16*)dout)[o] = f2bf(v);
    else     ((float*)dout)[o] = v;
}

extern "C" void kernel_launch(void* const* d_in, const int* in_sizes, int n_in,
                              void* d_out, int out_size, void* d_ws, size_t ws_size,
                              hipStream_t stream)
{
    const void* state  = d_in[0];
    const void* act    = d_in[1];
    const void* latent = d_in[2];
    const void* fcW    = d_in[3];
    const void* fcb    = d_in[4];
    const void* fc1W   = d_in[5];
    const void* fc2W   = d_in[6];
    const void* WW     = d_in[7];
    const void* rwW    = d_in[8];
    const void* rwb    = d_in[9];
    char* ws = (char*)d_ws;

    // ws layout: small path 6.43 MB; big path (+fc1s) 14.81 MB (gated on ws_size)
    int*   flag   = (int*)  (ws + 0);
    u16*   hs     = (u16*)  (ws + 1024);
    u16*   h      = (u16*)  (ws + 1147904);
    u16*   x1     = (u16*)  (ws + 2196480);
    u16*   x2     = (u16*)  (ws + 3245056);
    float* cbuf   = (float*)(ws + 4293632);
    float* rewbuf = (float*)(ws + 6390784);
    u16*   fc1s   = (u16*)  (ws + 6423552);
    const bool big = ws_size >= 14812160ull;       // launch-invariant -> graph-safe

    detect_k<<<dim3(1), dim3(64), 0, stream>>>((const u32*)state, flag);
    prep_k<<<dim3(4096), dim3(256), 0, stream>>>(state, act, latent, fc1W,
                                                 hs, fc1s, rewbuf, flag, big ? 1 : 0);

    // hidden = cell = relu(fc(hs0))
    gemm_k<2240, true, true, false, false, false><<<dim3(256), dim3(256), 0, stream>>>(
        hs, fcW, fcb, h, cbuf, nullptr, nullptr, 0, flag);

    for (int t = 0; t < 32; t++) {
        // x1 = relu(h @ fc1sum^T); by==0 blocks also copy act_t into hs
        if (big)
            gemm_k<2048, false, false, false, true, true><<<dim3(256), dim3(256), 0, stream>>>(
                h, fc1s, nullptr, x1, nullptr, hs, act, t, flag);
        else
            gemm_k<2048, false, false, true, true, false><<<dim3(256), dim3(256), 0, stream>>>(
                h, fc1W, nullptr, x1, nullptr, hs, act, t, flag);
        // x2 = relu(x1 @ fc2^T)
        gemm_k<2048, false, false, false, false, false><<<dim3(256), dim3(256), 0, stream>>>(
            x1, fc2W, nullptr, x2, nullptr, nullptr, nullptr, 0, flag);
        // cc = relu(x2 @ W_W^T) fused with gates/cell/h'/preds/reward-partial
        wgates_k<<<dim3(256), dim3(256), 0, stream>>>(
            x2, WW, cbuf, hs, d_out, rwW, rewbuf, t, flag);
        // h = relu(hs @ fc_W^T + b)   (carry discarded at t=31)
        if (t < 31)
            gemm_k<2240, true, false, false, false, false><<<dim3(256), dim3(256), 0, stream>>>(
                hs, fcW, fcb, h, nullptr, nullptr, nullptr, 0, flag);
    }
    rewfin_k<<<dim3(32), dim3(256), 0, stream>>>(rewbuf, d_out, rwb, flag);
}